// Round 15
// baseline (58.371 us; speedup 1.0000x reference)
//
#include <hip/hip_runtime.h>

#define NN 50000
#define DD 50
#define RR 64
#define BINS 2048                   // (rel, e&31) sub-bins
#define CAP 128                     // slots per bin (mean ~49; 11.5-sigma margin)
#define CAPN 24                     // per-node perm slots (in-degree ~Poisson(2))

// meta ints: bin cursors | node cursors | perm | int2 slots
#define BINCUR_OFF 0                                   // 2048
#define DCUR_OFF   2048                                // 50000
#define PERM_OFF   52048                               // 50000*24 = 1200000
#define SD_OFF     1252048                             // 2*BINS*CAP = 524288
#define META_INTS  1776336
#define WB_BYTE    ((size_t)META_INTS * 4)             // 7,105,344
#define MSG_BYTE   (WB_BYTE + (size_t)RR * 64 * 64 * 2)        // +512KB = 7,629,632
#define WS_NEED    (MSG_BYTE + (size_t)BINS * CAP * 64 * 2)    // ~41.2 MB

typedef __attribute__((ext_vector_type(8))) short bf16x8;
typedef __attribute__((ext_vector_type(4))) float f32x4;

__device__ __forceinline__ unsigned short f2b(float f) {   // f32 -> bf16 RNE
    unsigned u = __float_as_uint(f);
    u = (u + 0x7fffu + ((u >> 16) & 1u)) >> 16;
    return (unsigned short)u;
}

// A-fragment from a raw f32 h row (k-step 0: k=ch*8..+7 < 32 in-bounds;
// k-step 1: k=32+ch*8..+7, pairs fully inside the 50-elem row only).
__device__ __forceinline__ void load_a(const float* __restrict__ hrow, int ch,
                                       bf16x8& a0, bf16x8& a1) {
    const float2* hp0 = (const float2*)(hrow + ch * 8);
    float2 q0 = hp0[0], q1 = hp0[1], q2 = hp0[2], q3 = hp0[3];
    int kb = 32 + ch * 8;
    const float2 z2 = make_float2(0.f, 0.f);
    float2 q4 = (kb + 1 < DD) ? *(const float2*)(hrow + kb)     : z2;
    float2 q5 = (kb + 3 < DD) ? *(const float2*)(hrow + kb + 2) : z2;
    float2 q6 = (kb + 5 < DD) ? *(const float2*)(hrow + kb + 4) : z2;
    float2 q7 = (kb + 7 < DD) ? *(const float2*)(hrow + kb + 6) : z2;
    a0[0] = f2b(q0.x); a0[1] = f2b(q0.y); a0[2] = f2b(q1.x); a0[3] = f2b(q1.y);
    a0[4] = f2b(q2.x); a0[5] = f2b(q2.y); a0[6] = f2b(q3.x); a0[7] = f2b(q3.y);
    a1[0] = f2b(q4.x); a1[1] = f2b(q4.y); a1[2] = f2b(q5.x); a1[3] = f2b(q5.y);
    a1[4] = f2b(q6.x); a1[5] = f2b(q6.y); a1[6] = f2b(q7.x); a1[7] = f2b(q7.y);
}

// P0+P1 fused (independent work; cursors pre-zeroed by memsetAsync):
//  - wb[r][n][k] = bf16 W^T, 64x64 zero-padded, coalesced 2B writes
//  - scatter edges into (rel, e&31) bins
__global__ __launch_bounds__(256) void k_prep(int* __restrict__ meta,
        unsigned short* __restrict__ wb, const float* __restrict__ w,
        const int* __restrict__ src, const int* __restrict__ dst,
        const int* __restrict__ rel, int E) {
    int tid = blockIdx.x * 256 + threadIdx.x;
    int nth = gridDim.x * 256;
    for (int j = tid; j < RR * 64 * 64; j += nth) {
        int r = j >> 12, n = (j >> 6) & 63, d = j & 63;   // consecutive tid -> consecutive d
        float v = (n < DD && d < DD) ? w[r * (DD * DD) + d * DD + n] : 0.f;
        wb[j] = f2b(v);
    }
    for (int e = tid; e < E; e += nth) {
        int sb = (rel[e] << 5) | (e & 31);
        int p = atomicAdd(&meta[BINCUR_OFF + sb], 1);
        if (p < CAP)                                 // never fires at 11.5 sigma
            ((int2*)(meta + SD_OFF))[sb * CAP + p] = make_int2(src[e], dst[e]);
    }
}

// P2: one wave = quarter-bin = 32 edges (2 MFMA groups), single relation.
// Direct f32 h gather; B-frags loaded once, reused by both groups.
__global__ __launch_bounds__(256) void k_edge(const float* __restrict__ h,
        const unsigned short* __restrict__ wb, int* __restrict__ meta,
        unsigned short* __restrict__ msg) {
    int lane = threadIdx.x & 63;
    int wv = (blockIdx.x << 2) + (threadIdx.x >> 6);     // 0..8191
    int b = wv >> 2, qt = wv & 3;
    int cnt = __builtin_amdgcn_readfirstlane(meta[BINCUR_OFF + b]);
    if (cnt > CAP) cnt = CAP;
    int avail = cnt - (qt << 5);
    if (avail <= 0) return;
    if (avail > 32) avail = 32;
    int r = b >> 5;
    int slotbase = (b << 7) + (qt << 5);

    int2 sd = make_int2(0, -1);
    if (lane < avail) sd = ((const int2*)(meta + SD_OFF))[slotbase + lane];
    if (lane < avail) {                                   // perm append
        int pos = atomicAdd(&meta[DCUR_OFF + sd.y], 1);
        if (pos < CAPN)                                   // P ~ 1e-18, guard anyway
            meta[PERM_OFF + sd.y * CAPN + pos] = slotbase + lane;
    }
    int ch = lane >> 4, col0 = lane & 15;

    int sv0 = __shfl(sd.x, col0);
    int sv1 = __shfl(sd.x, 16 + col0);
    bf16x8 a00, a01, a10, a11;
    load_a(h + (size_t)sv0 * DD, ch, a00, a01);
    load_a(h + (size_t)sv1 * DD, ch, a10, a11);

    const unsigned short* wr = wb + ((size_t)r << 12) + (col0 << 6) + (ch << 3);
    bf16x8 bb0[4], bb1[4];
    #pragma unroll
    for (int t = 0; t < 4; ++t) {
        bb0[t] = *(const bf16x8*)(wr + t * 1024);
        bb1[t] = *(const bf16x8*)(wr + t * 1024 + 32);
    }

    {   // group 0: rows slotbase .. +15
        f32x4 c[4];
        #pragma unroll
        for (int t = 0; t < 4; ++t) {
            c[t] = (f32x4){0.f, 0.f, 0.f, 0.f};
            c[t] = __builtin_amdgcn_mfma_f32_16x16x32_bf16(a00, bb0[t], c[t], 0, 0, 0);
            c[t] = __builtin_amdgcn_mfma_f32_16x16x32_bf16(a01, bb1[t], c[t], 0, 0, 0);
        }
        // C layout (m89): col = t*16+col0, row = ch*4+q
        unsigned short* mb = msg + (size_t)(slotbase + (ch << 2)) * 64;
        #pragma unroll
        for (int q = 0; q < 4; ++q)
            #pragma unroll
            for (int t = 0; t < 4; ++t)
                mb[q * 64 + t * 16 + col0] = f2b(c[t][q]);
    }
    if (avail > 16) {   // group 1: rows slotbase+16 .. +31
        f32x4 c[4];
        #pragma unroll
        for (int t = 0; t < 4; ++t) {
            c[t] = (f32x4){0.f, 0.f, 0.f, 0.f};
            c[t] = __builtin_amdgcn_mfma_f32_16x16x32_bf16(a10, bb0[t], c[t], 0, 0, 0);
            c[t] = __builtin_amdgcn_mfma_f32_16x16x32_bf16(a11, bb1[t], c[t], 0, 0, 0);
        }
        unsigned short* mb = msg + (size_t)(slotbase + 16 + (ch << 2)) * 64;
        #pragma unroll
        for (int q = 0; q < 4; ++q)
            #pragma unroll
            for (int t = 0; t < 4; ++t)
                mb[q * 64 + t * 16 + col0] = f2b(c[t][q]);
    }
}

// P3: one wave per node: cnt + batched int4 perm prefetch, independent bf16
// msg-row reads, +bias, relu, store (each output row written exactly once).
__global__ __launch_bounds__(256) void k_agg(const unsigned short* __restrict__ msg,
        const int* __restrict__ meta, const float* __restrict__ bias,
        float* __restrict__ out) {
    int lane = threadIdx.x & 63;
    int n = (blockIdx.x << 2) + (threadIdx.x >> 6);
    if (n >= NN) return;
    int cnt = __builtin_amdgcn_readfirstlane(meta[DCUR_OFF + n]);
    if (cnt > CAPN) cnt = CAPN;
    float v = 0.f;
    const int4* pp = (const int4*)(meta + PERM_OFF + n * CAPN);
    int4 P0 = pp[0], P1 = pp[1];                  // covers deg<=8 (99.98%)
    int pj[8] = {P0.x, P0.y, P0.z, P0.w, P1.x, P1.y, P1.z, P1.w};
    #pragma unroll
    for (int j = 0; j < 8; ++j) {
        if (j < cnt) {
            unsigned short u = msg[(size_t)pj[j] * 64 + lane];
            v += __uint_as_float((unsigned)u << 16);
        }
    }
    #pragma unroll 1
    for (int j = 8; j < cnt; ++j) {               // rare tail
        int p = meta[PERM_OFF + n * CAPN + j];
        unsigned short u = msg[(size_t)p * 64 + lane];
        v += __uint_as_float((unsigned)u << 16);
    }
    if (lane < DD) {
        float o = v + bias[lane];
        out[(size_t)n * DD + lane] = o > 0.f ? o : 0.f;
    }
}

// ---------- tiny-ws fallback: round-1 style atomics ----------
__global__ void fb_edge_kernel(const float* __restrict__ h, const float* __restrict__ weight,
                               const int* __restrict__ src_idx, const int* __restrict__ dst_idx,
                               const int* __restrict__ rel_type, float* __restrict__ acc, int E) {
    int wave = (int)((blockIdx.x * blockDim.x + threadIdx.x) >> 6);
    int lane = threadIdx.x & 63;
    if (wave >= E) return;
    int s = src_idx[wave], r = rel_type[wave], dn = dst_idx[wave];
    const float* hs = h + (size_t)s * DD;
    const float* W  = weight + (size_t)r * DD * DD;
    if (lane < DD) {
        float m = 0.f;
        for (int d = 0; d < DD; ++d) m = fmaf(hs[d], W[d * DD + lane], m);
        atomicAdd(&acc[(size_t)dn * DD + lane], m);
    }
}
__global__ void fb_finalize_kernel(float* __restrict__ out, const float* __restrict__ bias, int total) {
    int i = blockIdx.x * blockDim.x + threadIdx.x;
    if (i < total) {
        float v = out[i] + bias[i % DD];
        out[i] = v > 0.f ? v : 0.f;
    }
}

extern "C" void kernel_launch(void* const* d_in, const int* in_sizes, int n_in,
                              void* d_out, int out_size, void* d_ws, size_t ws_size,
                              hipStream_t stream) {
    const float* h      = (const float*)d_in[0];
    const float* weight = (const float*)d_in[1];
    const float* bias   = (const float*)d_in[2];
    const int*   src    = (const int*)d_in[3];
    const int*   dst    = (const int*)d_in[4];
    const int*   rel    = (const int*)d_in[5];
    float* out = (float*)d_out;
    int E = in_sizes[3];

    if (ws_size >= WS_NEED) {
        int* meta = (int*)d_ws;
        unsigned short* wb  = (unsigned short*)((char*)d_ws + WB_BYTE);
        unsigned short* msg = (unsigned short*)((char*)d_ws + MSG_BYTE);

        hipMemsetAsync(meta, 0, (size_t)(BINS + NN) * 4, stream);   // all cursors
        k_prep<<<1024, 256, 0, stream>>>(meta, wb, weight, src, dst, rel, E);
        k_edge<<<2048, 256, 0, stream>>>(h, wb, meta, msg);
        k_agg<<<(NN + 3) / 4, 256, 0, stream>>>(msg, meta, bias, out);
    } else {
        hipMemsetAsync(out, 0, (size_t)out_size * sizeof(float), stream);
        fb_edge_kernel<<<(E + 3) / 4, 256, 0, stream>>>(h, weight, src, dst, rel, out, E);
        fb_finalize_kernel<<<(out_size + 255) / 256, 256, 0, stream>>>(out, bias, out_size);
    }
}

// Round 16
// 58.072 us; speedup vs baseline: 1.0052x; 1.0052x over previous
//
#include <hip/hip_runtime.h>

#define NN 50000
#define DD 50
#define RR 64
#define BINS 2048                   // (rel, e&31) sub-bins
#define CAP 128                     // slots per bin (mean ~49; 11.5-sigma margin)
#define CAPN 24                     // per-node perm slots (in-degree ~Poisson(2))

// meta ints: bin cursors | node cursors | perm | int2 slots
#define BINCUR_OFF 0                                   // 2048
#define DCUR_OFF   2048                                // 50000
#define PERM_OFF   52048                               // 50000*24 = 1200000
#define SD_OFF     1252048                             // 2*BINS*CAP = 524288
#define META_INTS  1776336
#define WB_BYTE    ((size_t)META_INTS * 4)             // 7,105,344
#define MSG_BYTE   (WB_BYTE + (size_t)RR * 64 * 64 * 2)        // +512KB = 7,629,632
#define WS_NEED    (MSG_BYTE + (size_t)BINS * CAP * 64 * 2)    // ~41.2 MB

#define NCUR (BINS + NN)            // 52048 cursor ints

typedef __attribute__((ext_vector_type(8))) short bf16x8;
typedef __attribute__((ext_vector_type(4))) float f32x4;

__device__ __forceinline__ unsigned short f2b(float f) {   // f32 -> bf16 RNE
    unsigned u = __float_as_uint(f);
    u = (u + 0x7fffu + ((u >> 16) & 1u)) >> 16;
    return (unsigned short)u;
}

// Zero all cursors. Replaces hipMemsetAsync: the runtime's fillBufferAligned
// ran a 203 KB fill at 5 GB/s (41 us, round-15 rocprof). One store per thread.
__global__ __launch_bounds__(256) void k_zero(int* __restrict__ meta) {
    int i = blockIdx.x * 256 + threadIdx.x;
    if (i < NCUR) meta[i] = 0;
}

// A-fragment from a raw f32 h row (k-step 0: k=ch*8..+7 < 32 in-bounds;
// k-step 1: k=32+ch*8..+7, pairs fully inside the 50-elem row only).
__device__ __forceinline__ void load_a(const float* __restrict__ hrow, int ch,
                                       bf16x8& a0, bf16x8& a1) {
    const float2* hp0 = (const float2*)(hrow + ch * 8);
    float2 q0 = hp0[0], q1 = hp0[1], q2 = hp0[2], q3 = hp0[3];
    int kb = 32 + ch * 8;
    const float2 z2 = make_float2(0.f, 0.f);
    float2 q4 = (kb + 1 < DD) ? *(const float2*)(hrow + kb)     : z2;
    float2 q5 = (kb + 3 < DD) ? *(const float2*)(hrow + kb + 2) : z2;
    float2 q6 = (kb + 5 < DD) ? *(const float2*)(hrow + kb + 4) : z2;
    float2 q7 = (kb + 7 < DD) ? *(const float2*)(hrow + kb + 6) : z2;
    a0[0] = f2b(q0.x); a0[1] = f2b(q0.y); a0[2] = f2b(q1.x); a0[3] = f2b(q1.y);
    a0[4] = f2b(q2.x); a0[5] = f2b(q2.y); a0[6] = f2b(q3.x); a0[7] = f2b(q3.y);
    a1[0] = f2b(q4.x); a1[1] = f2b(q4.y); a1[2] = f2b(q5.x); a1[3] = f2b(q5.y);
    a1[4] = f2b(q6.x); a1[5] = f2b(q6.y); a1[6] = f2b(q7.x); a1[7] = f2b(q7.y);
}

// wb build + edge scatter fused (independent work; cursors zeroed by k_zero):
//  - wb[r][n][k] = bf16 W^T, 64x64 zero-padded, coalesced 2B writes
//  - scatter edges into (rel, e&31) bins
__global__ __launch_bounds__(256) void k_prep(int* __restrict__ meta,
        unsigned short* __restrict__ wb, const float* __restrict__ w,
        const int* __restrict__ src, const int* __restrict__ dst,
        const int* __restrict__ rel, int E) {
    int tid = blockIdx.x * 256 + threadIdx.x;
    int nth = gridDim.x * 256;
    for (int j = tid; j < RR * 64 * 64; j += nth) {
        int r = j >> 12, n = (j >> 6) & 63, d = j & 63;   // consecutive tid -> consecutive d
        float v = (n < DD && d < DD) ? w[r * (DD * DD) + d * DD + n] : 0.f;
        wb[j] = f2b(v);
    }
    for (int e = tid; e < E; e += nth) {
        int sb = (rel[e] << 5) | (e & 31);
        int p = atomicAdd(&meta[BINCUR_OFF + sb], 1);
        if (p < CAP)                                 // never fires at 11.5 sigma
            ((int2*)(meta + SD_OFF))[sb * CAP + p] = make_int2(src[e], dst[e]);
    }
}

// One wave = quarter-bin = 32 edges (2 MFMA groups), single relation.
// Direct f32 h gather; B-frags loaded once, reused by both groups.
__global__ __launch_bounds__(256) void k_edge(const float* __restrict__ h,
        const unsigned short* __restrict__ wb, int* __restrict__ meta,
        unsigned short* __restrict__ msg) {
    int lane = threadIdx.x & 63;
    int wv = (blockIdx.x << 2) + (threadIdx.x >> 6);     // 0..8191
    int b = wv >> 2, qt = wv & 3;
    int cnt = __builtin_amdgcn_readfirstlane(meta[BINCUR_OFF + b]);
    if (cnt > CAP) cnt = CAP;
    int avail = cnt - (qt << 5);
    if (avail <= 0) return;
    if (avail > 32) avail = 32;
    int r = b >> 5;
    int slotbase = (b << 7) + (qt << 5);

    int2 sd = make_int2(0, -1);
    if (lane < avail) sd = ((const int2*)(meta + SD_OFF))[slotbase + lane];
    if (lane < avail) {                                   // perm append
        int pos = atomicAdd(&meta[DCUR_OFF + sd.y], 1);
        if (pos < CAPN)                                   // P ~ 1e-18, guard anyway
            meta[PERM_OFF + sd.y * CAPN + pos] = slotbase + lane;
    }
    int ch = lane >> 4, col0 = lane & 15;

    int sv0 = __shfl(sd.x, col0);
    int sv1 = __shfl(sd.x, 16 + col0);
    bf16x8 a00, a01, a10, a11;
    load_a(h + (size_t)sv0 * DD, ch, a00, a01);
    load_a(h + (size_t)sv1 * DD, ch, a10, a11);

    const unsigned short* wr = wb + ((size_t)r << 12) + (col0 << 6) + (ch << 3);
    bf16x8 bb0[4], bb1[4];
    #pragma unroll
    for (int t = 0; t < 4; ++t) {
        bb0[t] = *(const bf16x8*)(wr + t * 1024);
        bb1[t] = *(const bf16x8*)(wr + t * 1024 + 32);
    }

    {   // group 0: rows slotbase .. +15
        f32x4 c[4];
        #pragma unroll
        for (int t = 0; t < 4; ++t) {
            c[t] = (f32x4){0.f, 0.f, 0.f, 0.f};
            c[t] = __builtin_amdgcn_mfma_f32_16x16x32_bf16(a00, bb0[t], c[t], 0, 0, 0);
            c[t] = __builtin_amdgcn_mfma_f32_16x16x32_bf16(a01, bb1[t], c[t], 0, 0, 0);
        }
        // C layout (m89): col = t*16+col0, row = ch*4+q
        unsigned short* mb = msg + (size_t)(slotbase + (ch << 2)) * 64;
        #pragma unroll
        for (int q = 0; q < 4; ++q)
            #pragma unroll
            for (int t = 0; t < 4; ++t)
                mb[q * 64 + t * 16 + col0] = f2b(c[t][q]);
    }
    if (avail > 16) {   // group 1: rows slotbase+16 .. +31
        f32x4 c[4];
        #pragma unroll
        for (int t = 0; t < 4; ++t) {
            c[t] = (f32x4){0.f, 0.f, 0.f, 0.f};
            c[t] = __builtin_amdgcn_mfma_f32_16x16x32_bf16(a10, bb0[t], c[t], 0, 0, 0);
            c[t] = __builtin_amdgcn_mfma_f32_16x16x32_bf16(a11, bb1[t], c[t], 0, 0, 0);
        }
        unsigned short* mb = msg + (size_t)(slotbase + 16 + (ch << 2)) * 64;
        #pragma unroll
        for (int q = 0; q < 4; ++q)
            #pragma unroll
            for (int t = 0; t < 4; ++t)
                mb[q * 64 + t * 16 + col0] = f2b(c[t][q]);
    }
}

// One wave per node: cnt + batched int4 perm prefetch, independent bf16
// msg-row reads, +bias, relu, store (each output row written exactly once).
__global__ __launch_bounds__(256) void k_agg(const unsigned short* __restrict__ msg,
        const int* __restrict__ meta, const float* __restrict__ bias,
        float* __restrict__ out) {
    int lane = threadIdx.x & 63;
    int n = (blockIdx.x << 2) + (threadIdx.x >> 6);
    if (n >= NN) return;
    int cnt = __builtin_amdgcn_readfirstlane(meta[DCUR_OFF + n]);
    if (cnt > CAPN) cnt = CAPN;
    float v = 0.f;
    const int4* pp = (const int4*)(meta + PERM_OFF + n * CAPN);
    int4 P0 = pp[0], P1 = pp[1];                  // covers deg<=8 (99.98%)
    int pj[8] = {P0.x, P0.y, P0.z, P0.w, P1.x, P1.y, P1.z, P1.w};
    #pragma unroll
    for (int j = 0; j < 8; ++j) {
        if (j < cnt) {
            unsigned short u = msg[(size_t)pj[j] * 64 + lane];
            v += __uint_as_float((unsigned)u << 16);
        }
    }
    #pragma unroll 1
    for (int j = 8; j < cnt; ++j) {               // rare tail
        int p = meta[PERM_OFF + n * CAPN + j];
        unsigned short u = msg[(size_t)p * 64 + lane];
        v += __uint_as_float((unsigned)u << 16);
    }
    if (lane < DD) {
        float o = v + bias[lane];
        out[(size_t)n * DD + lane] = o > 0.f ? o : 0.f;
    }
}

// ---------- tiny-ws fallback: round-1 style atomics ----------
__global__ void fb_edge_kernel(const float* __restrict__ h, const float* __restrict__ weight,
                               const int* __restrict__ src_idx, const int* __restrict__ dst_idx,
                               const int* __restrict__ rel_type, float* __restrict__ acc, int E) {
    int wave = (int)((blockIdx.x * blockDim.x + threadIdx.x) >> 6);
    int lane = threadIdx.x & 63;
    if (wave >= E) return;
    int s = src_idx[wave], r = rel_type[wave], dn = dst_idx[wave];
    const float* hs = h + (size_t)s * DD;
    const float* W  = weight + (size_t)r * DD * DD;
    if (lane < DD) {
        float m = 0.f;
        for (int d = 0; d < DD; ++d) m = fmaf(hs[d], W[d * DD + lane], m);
        atomicAdd(&acc[(size_t)dn * DD + lane], m);
    }
}
__global__ void fb_zero_kernel(float* __restrict__ out, int total) {
    int i = blockIdx.x * blockDim.x + threadIdx.x;
    if (i < total) out[i] = 0.f;
}
__global__ void fb_finalize_kernel(float* __restrict__ out, const float* __restrict__ bias, int total) {
    int i = blockIdx.x * blockDim.x + threadIdx.x;
    if (i < total) {
        float v = out[i] + bias[i % DD];
        out[i] = v > 0.f ? v : 0.f;
    }
}

extern "C" void kernel_launch(void* const* d_in, const int* in_sizes, int n_in,
                              void* d_out, int out_size, void* d_ws, size_t ws_size,
                              hipStream_t stream) {
    const float* h      = (const float*)d_in[0];
    const float* weight = (const float*)d_in[1];
    const float* bias   = (const float*)d_in[2];
    const int*   src    = (const int*)d_in[3];
    const int*   dst    = (const int*)d_in[4];
    const int*   rel    = (const int*)d_in[5];
    float* out = (float*)d_out;
    int E = in_sizes[3];

    if (ws_size >= WS_NEED) {
        int* meta = (int*)d_ws;
        unsigned short* wb  = (unsigned short*)((char*)d_ws + WB_BYTE);
        unsigned short* msg = (unsigned short*)((char*)d_ws + MSG_BYTE);

        k_zero<<<(NCUR + 255) / 256, 256, 0, stream>>>(meta);
        k_prep<<<1024, 256, 0, stream>>>(meta, wb, weight, src, dst, rel, E);
        k_edge<<<2048, 256, 0, stream>>>(h, wb, meta, msg);
        k_agg<<<(NN + 3) / 4, 256, 0, stream>>>(msg, meta, bias, out);
    } else {
        fb_zero_kernel<<<(out_size + 255) / 256, 256, 0, stream>>>(out, out_size);
        fb_edge_kernel<<<(E + 3) / 4, 256, 0, stream>>>(h, weight, src, dst, rel, out, E);
        fb_finalize_kernel<<<(out_size + 255) / 256, 256, 0, stream>>>(out, bias, out_size);
    }
}